// Round 6
// baseline (283.093 us; speedup 1.0000x reference)
//
#include <hip/hip_runtime.h>

// SimpleSelfAttention: B=4, S=2048, D=1024, fp32 in/out, bf16 MFMA internally.
// R6: same proven 16x16x32/BK=64 core (0 conflicts). Topology: QK(z=2)+Vt
//     merged into one 1536-block launch (tail packing); PV re-tiled to
//     64x128 -> 1024 blocks (4/CU, was 2/CU). 5 dispatches.

typedef __attribute__((ext_vector_type(8))) short short8;
typedef __attribute__((ext_vector_type(4))) short short4v;
typedef __attribute__((ext_vector_type(4))) float float4v;

__device__ __forceinline__ short f2bf(float f) {
  unsigned u = __builtin_bit_cast(unsigned, f);
  u += 0x7fffu + ((u >> 16) & 1u);  // RNE; inputs finite
  return (short)(u >> 16);
}
__device__ __forceinline__ float bf2f(short s) {
  unsigned u = ((unsigned)(unsigned short)s) << 16;
  return __builtin_bit_cast(float, u);
}

// async global->LDS, 16B per lane. LDS dest = wave-uniform base + lane*16.
__device__ __forceinline__ void gl2lds16(const void* g, void* l) {
  __builtin_amdgcn_global_load_lds((const __attribute__((address_space(1))) void*)g,
                                   (__attribute__((address_space(3))) void*)l, 16, 0, 0);
}

// ---------- merged prep: w cvt (3x1024^2) + x cvt (8192x1024) + bias concat ----------
__global__ __launch_bounds__(256) void prep_kernel(const float* __restrict__ x,
                                                   const float* __restrict__ wq,
                                                   const float* __restrict__ wk,
                                                   const float* __restrict__ wv,
                                                   const float* __restrict__ bq,
                                                   const float* __restrict__ bk,
                                                   short* __restrict__ x_bf,
                                                   short* __restrict__ w_bf,
                                                   float* __restrict__ bcat) {
  int b = blockIdx.x;
  if (b < 3072) {                      // weights
    int seg = b >> 10;                 // 0,1,2 (wave-uniform)
    const float* w = seg == 0 ? wq : (seg == 1 ? wk : wv);
    int i = (b - (seg << 10)) * 256 + threadIdx.x;
    float4v v = ((const float4v*)w)[i];
    short4v o;
    o.x = f2bf(v.x); o.y = f2bf(v.y); o.z = f2bf(v.z); o.w = f2bf(v.w);
    ((short4v*)(w_bf + (long)seg * 1048576))[i] = o;
  } else if (b < 11264) {              // x
    int i = (b - 3072) * 256 + threadIdx.x;  // < 2097152
    float4v v = ((const float4v*)x)[i];
    short4v o;
    o.x = f2bf(v.x); o.y = f2bf(v.y); o.z = f2bf(v.z); o.w = f2bf(v.w);
    ((short4v*)x_bf)[i] = o;
  } else {                             // Q,K biases (bv handled by Vt gemm)
    int i = (b - 11264) * 256 + threadIdx.x;
    if (i < 2048) bcat[i] = i < 1024 ? bq[i] : bk[i - 1024];
  }
}

__global__ __launch_bounds__(256) void zero_rs(float* __restrict__ rs) {
  rs[blockIdx.x * 256 + threadIdx.x] = 0.f;
}

// ---------- shared GEMM body: C[m,n] = sum_k A[m,k]*B[n,k], BMx128 tile, BK=64 ----
// LDS: 16B chunk c of row r stored at slot c ^ (r&7); reader slot
// (s*4+quad) ^ (col&7) -- measured 0 bank conflicts (R3/R5).
// EPI 0: +aux[n], store bf16.   EPI 1: store bf16 exp(v*scale + aux[m*N+n]),
//   atomicAdd row sums into rsum[m].   EPI 2: store fp32 v * rcp(aux[m]).
// EPI 3: +aux[m], store bf16.
// All pointers pre-offset per batch by the caller.
template <int EPI, int BM>
__device__ __forceinline__ void gemm_body(const short* __restrict__ A,
                                          const short* __restrict__ Bm,
                                          void* __restrict__ C,
                                          const float* __restrict__ aux,
                                          float* __restrict__ rsum, float scale,
                                          int N, int Kd, int Bld, int m0, int n0,
                                          short (*As)[64], short (*Bs)[64]) {
  constexpr int WI = BM / 32;  // #16-row subtiles per wave in m
  const int t = threadIdx.x;
  const int lane = t & 63, wave = t >> 6;
  const int wm = (wave & 1) * (BM / 2), wn = (wave >> 1) * 64;
  const int col = lane & 15, quad = lane >> 4;

  const int r_loc = lane >> 3, slot = lane & 7;
  const int cch = slot ^ r_loc;  // global chunk that belongs in this slot
  const int sw = col & 7;        // reader swizzle

  float4v acc[WI][4] = {};

  for (int kt = 0; kt < Kd; kt += 64) {
#pragma unroll
    for (int u = 0; u < WI; ++u) {  // A: BM rows
      const int rowbase = wave * (BM / 4) + u * 8;
      gl2lds16(&A[(long)(m0 + rowbase + r_loc) * Kd + kt + cch * 8],
               &As[rowbase][0] + lane * 8);
    }
#pragma unroll
    for (int u = 0; u < 4; ++u) {   // B: 128 rows
      const int rowbase = wave * 32 + u * 8;
      gl2lds16(&Bm[(long)(n0 + rowbase + r_loc) * Bld + kt + cch * 8],
               &Bs[rowbase][0] + lane * 8);
    }
    __syncthreads();

#pragma unroll
    for (int s = 0; s < 2; ++s) {
      short8 af[WI], bfr[4];
#pragma unroll
      for (int i = 0; i < WI; ++i)
        af[i] = *(const short8*)&As[wm + i * 16 + col][((s * 4 + quad) ^ sw) * 8];
#pragma unroll
      for (int j = 0; j < 4; ++j)
        bfr[j] = *(const short8*)&Bs[wn + j * 16 + col][((s * 4 + quad) ^ sw) * 8];
#pragma unroll
      for (int i = 0; i < WI; ++i)
#pragma unroll
        for (int j = 0; j < 4; ++j)
          acc[i][j] = __builtin_amdgcn_mfma_f32_16x16x32_bf16(af[i], bfr[j], acc[i][j], 0, 0, 0);
    }
    __syncthreads();
  }

  // C/D layout: col = lane&15, row = quad*4 + reg  (m89-verified)
  const float LOG2E = 1.44269504f;
  const float c1 = scale * LOG2E;
#pragma unroll
  for (int i = 0; i < WI; ++i) {
    float invv[4], addm[4], rsum4[4] = {0.f, 0.f, 0.f, 0.f};
    if (EPI == 2) {
#pragma unroll
      for (int r = 0; r < 4; ++r)
        invv[r] = __builtin_amdgcn_rcpf(aux[m0 + wm + i * 16 + quad * 4 + r]);
    }
    if (EPI == 3) {
#pragma unroll
      for (int r = 0; r < 4; ++r) addm[r] = aux[m0 + wm + i * 16 + quad * 4 + r];
    }
#pragma unroll
    for (int j = 0; j < 4; ++j) {
      const int n = n0 + wn + j * 16 + col;
      float addn = 0.f;
      if (EPI == 0) addn = aux[n];
#pragma unroll
      for (int r = 0; r < 4; ++r) {
        const int m = m0 + wm + i * 16 + quad * 4 + r;
        float v = acc[i][j][r];
        if (EPI == 0) {
          ((short*)C)[(long)m * N + n] = f2bf(v + addn);
        } else if (EPI == 1) {
          float mv = aux[(long)m * N + n];
          float e = exp2f(fmaf(v, c1, mv * LOG2E));  // exp(v*scale+mask); |s|~3, safe
          short q = f2bf(e);
          ((short*)C)[(long)m * N + n] = q;
          rsum4[r] += bf2f(q);  // sum exactly what PV will read
        } else if (EPI == 2) {
          ((float*)C)[(long)m * N + n] = v * invv[r];
        } else {
          ((short*)C)[(long)m * N + n] = f2bf(v + addm[r]);
        }
      }
    }
    if (EPI == 1) {
#pragma unroll
      for (int r = 0; r < 4; ++r) {
        float s = rsum4[r];
        s += __shfl_xor(s, 1);
        s += __shfl_xor(s, 2);
        s += __shfl_xor(s, 4);
        s += __shfl_xor(s, 8);
        if (col == 0) atomicAdd(&rsum[m0 + wm + i * 16 + quad * 4 + r], s);
      }
    }
  }
}

// ---------- QK (z=2, blocks 0..1023) + Vt (blocks 1024..1535) in one launch ----------
__global__ __launch_bounds__(256) void qkv_kernel(const short* __restrict__ x_bf,
                                                  const short* __restrict__ w_bf,
                                                  short* __restrict__ QK,
                                                  short* __restrict__ Vt,
                                                  const float* __restrict__ bcat,
                                                  const float* __restrict__ bv) {
  __shared__ alignas(16) short As[128][64];
  __shared__ alignas(16) short Bs[128][64];
  const int b = blockIdx.x;
  if (b < 1024) {
    const int bz = b >> 9, r = b & 511;          // (64 m-blocks) x (8 n-blocks)
    gemm_body<0, 128>(x_bf, w_bf + (long)bz * 1048576, QK + (long)bz * 8388608,
                      bcat + bz * 1024, nullptr, 1.f,
                      1024, 1024, 1024, (r & 63) * 128, (r >> 6) * 128, As, Bs);
  } else {
    const int r = b - 1024;                      // (8 m-blocks) x (64 n-blocks)
    gemm_body<3, 128>(w_bf + 2097152, x_bf, Vt, bv, nullptr, 1.f,
                      8192, 1024, 1024, (r & 7) * 128, (r >> 3) * 128, As, Bs);
  }
}

// ---------- P = exp(Q K^T /32 + mask), rowsums into rs ----------
__global__ __launch_bounds__(256) void scores_kernel(const short* __restrict__ Q,
                                                     const short* __restrict__ Kb,
                                                     short* __restrict__ P,
                                                     const float* __restrict__ mask,
                                                     float* __restrict__ rs) {
  __shared__ alignas(16) short As[128][64];
  __shared__ alignas(16) short Bs[128][64];
  const int bz = blockIdx.z;
  gemm_body<1, 128>(Q + (long)bz * 2097152, Kb + (long)bz * 2097152,
                    P + (long)bz * 4194304, mask, rs + bz * 2048, 0.03125f,
                    2048, 1024, 1024, blockIdx.x * 128, blockIdx.y * 128, As, Bs);
}

// ---------- out = (P V) / rs, 64x128 tile (1024 blocks -> 4/CU) ----------
__global__ __launch_bounds__(256) void pv_kernel(const short* __restrict__ P,
                                                 const short* __restrict__ Vt,
                                                 float* __restrict__ out,
                                                 const float* __restrict__ rs) {
  __shared__ alignas(16) short As[64][64];
  __shared__ alignas(16) short Bs[128][64];
  const int bz = blockIdx.z;
  gemm_body<2, 64>(P + (long)bz * 4194304, Vt + (long)bz * 2048,
                   out + (long)bz * 2097152, rs + bz * 2048, nullptr, 1.f,
                   1024, 2048, 8192, blockIdx.x * 64, blockIdx.y * 128, As, Bs);
}

extern "C" void kernel_launch(void* const* d_in, const int* in_sizes, int n_in,
                              void* d_out, int out_size, void* d_ws, size_t ws_size,
                              hipStream_t stream) {
  const float* x    = (const float*)d_in[0];
  const float* mask = (const float*)d_in[1];
  const float* wq   = (const float*)d_in[2];
  const float* bq   = (const float*)d_in[3];
  const float* wk   = (const float*)d_in[4];
  const float* bk   = (const float*)d_in[5];
  const float* wv   = (const float*)d_in[6];
  const float* bv   = (const float*)d_in[7];
  float* out = (float*)d_out;

  char* ws = (char*)d_ws;
  const size_t MB = 1024 * 1024;
  short* x_bf = (short*)(ws);             // 16 MB [8192,1024]
  short* w_bf = (short*)(ws + 16 * MB);   // 6 MB [3][1024,1024]
  float* rs   = (float*)(ws + 16 * MB);   // 32 KB [4][2048]; aliases w_bf (dead after qkv)
  short* QK   = (short*)(ws + 22 * MB);   // 32 MB [2][8192,1024]
  short* Vt   = (short*)(ws + 54 * MB);   // 16 MB [1024][8192] = [d][b*2048+s]
  short* P    = (short*)(ws + 70 * MB);   // 32 MB [4][2048][2048] (unnormalized exp)
  float* bcat = (float*)(ws + 70 * MB);   // 8 KB, aliases head of P (dead before P written)

  prep_kernel<<<11272, 256, 0, stream>>>(x, wq, wk, wv, bq, bk, x_bf, w_bf, bcat);

  // QK projections (z=2) + Vt GEMM in one launch (1536 blocks, tail-packed)
  qkv_kernel<<<1536, 256, 0, stream>>>(x_bf, w_bf, QK, Vt, bcat, bv);

  zero_rs<<<32, 256, 0, stream>>>(rs);  // w_bf dead from here; rs aliases it

  short* Q  = QK;
  short* Kb = QK + 8388608;

  // P = exp(Q K^T / 32 + mask) -> bf16 unnormalized; rs[b][q] += row sums
  scores_kernel<<<dim3(16, 16, 4), 256, 0, stream>>>(Q, Kb, P, mask, rs);

  // out = (P V) / rs
  pv_kernel<<<dim3(32, 8, 4), 256, 0, stream>>>(P, Vt, out, rs);
}

// Round 8
// 272.993 us; speedup vs baseline: 1.0370x; 1.0370x over previous
//
#include <hip/hip_runtime.h>

// SimpleSelfAttention: B=4, S=2048, D=1024, fp32 in/out, bf16 MFMA internally.
// R8 = R7 + fix: rowsum partials get a slot PER (n-tile, wave-n-half)
//     [32][4][2048] -- R7's plain store had waves 0/2 (and 1/3) racing on the
//     same rsum[m] (they share m rows, split n). 4 dispatches.

typedef __attribute__((ext_vector_type(8))) short short8;
typedef __attribute__((ext_vector_type(4))) short short4v;
typedef __attribute__((ext_vector_type(4))) float float4v;

__device__ __forceinline__ short f2bf(float f) {
  unsigned u = __builtin_bit_cast(unsigned, f);
  u += 0x7fffu + ((u >> 16) & 1u);  // RNE; inputs finite
  return (short)(u >> 16);
}
__device__ __forceinline__ float bf2f(short s) {
  unsigned u = ((unsigned)(unsigned short)s) << 16;
  return __builtin_bit_cast(float, u);
}

// async global->LDS, 16B per lane. LDS dest = wave-uniform base + lane*16.
__device__ __forceinline__ void gl2lds16(const void* g, void* l) {
  __builtin_amdgcn_global_load_lds((const __attribute__((address_space(1))) void*)g,
                                   (__attribute__((address_space(3))) void*)l, 16, 0, 0);
}

// ---------- merged prep: w cvt (3x1024^2) + x cvt (8192x1024) + bias concat ----------
__global__ __launch_bounds__(256) void prep_kernel(const float* __restrict__ x,
                                                   const float* __restrict__ wq,
                                                   const float* __restrict__ wk,
                                                   const float* __restrict__ wv,
                                                   const float* __restrict__ bq,
                                                   const float* __restrict__ bk,
                                                   short* __restrict__ x_bf,
                                                   short* __restrict__ w_bf,
                                                   float* __restrict__ bcat) {
  int b = blockIdx.x;
  if (b < 3072) {                      // weights
    int seg = b >> 10;                 // 0,1,2 (wave-uniform)
    const float* w = seg == 0 ? wq : (seg == 1 ? wk : wv);
    int i = (b - (seg << 10)) * 256 + threadIdx.x;
    float4v v = ((const float4v*)w)[i];
    short4v o;
    o.x = f2bf(v.x); o.y = f2bf(v.y); o.z = f2bf(v.z); o.w = f2bf(v.w);
    ((short4v*)(w_bf + (long)seg * 1048576))[i] = o;
  } else if (b < 11264) {              // x
    int i = (b - 3072) * 256 + threadIdx.x;  // < 2097152
    float4v v = ((const float4v*)x)[i];
    short4v o;
    o.x = f2bf(v.x); o.y = f2bf(v.y); o.z = f2bf(v.z); o.w = f2bf(v.w);
    ((short4v*)x_bf)[i] = o;
  } else {                             // Q,K biases (bv handled by Vt gemm)
    int i = (b - 11264) * 256 + threadIdx.x;
    if (i < 2048) bcat[i] = i < 1024 ? bq[i] : bk[i - 1024];
  }
}

// ---------- shared GEMM body: C[m,n] = sum_k A[m,k]*B[n,k], 128x128 tile, BK=64 ----
// LDS: 16B chunk c of row r stored at slot c ^ (r&7); reader slot
// (s*4+quad) ^ (col&7) -- measured 0 bank conflicts (R3/R5/R6).
// EPI 0: +aux[n], store bf16.
// EPI 1: store bf16 exp(v*scale + aux[m*N+n]); per-(wave-n-half) partial row
//        sums -> rsum[(wn>>6)*8192 + m] (plain store, unique writer).
// EPI 2: rowsums = sum of 32 partials aux[p*8192+m]; store fp32 v * rcp(rowsum).
// EPI 3: +aux[m], store bf16.
// All pointers pre-offset per batch by the caller.
template <int EPI>
__device__ __forceinline__ void gemm_body(const short* __restrict__ A,
                                          const short* __restrict__ Bm,
                                          void* __restrict__ C,
                                          const float* __restrict__ aux,
                                          float* __restrict__ rsum, float scale,
                                          int N, int Kd, int Bld, int m0, int n0,
                                          short (*As)[64], short (*Bs)[64]) {
  const int t = threadIdx.x;
  const int lane = t & 63, wave = t >> 6;
  const int wm = (wave & 1) * 64, wn = (wave >> 1) * 64;
  const int col = lane & 15, quad = lane >> 4;

  const int r_loc = lane >> 3, slot = lane & 7;
  const int cch = slot ^ r_loc;  // global chunk that belongs in this slot
  const int sw = col & 7;        // reader swizzle

  float4v acc[4][4] = {};

  for (int kt = 0; kt < Kd; kt += 64) {
#pragma unroll
    for (int u = 0; u < 4; ++u) {
      const int rowbase = wave * 32 + u * 8;
      gl2lds16(&A[(long)(m0 + rowbase + r_loc) * Kd + kt + cch * 8],
               &As[rowbase][0] + lane * 8);
      gl2lds16(&Bm[(long)(n0 + rowbase + r_loc) * Bld + kt + cch * 8],
               &Bs[rowbase][0] + lane * 8);
    }
    __syncthreads();

#pragma unroll
    for (int s = 0; s < 2; ++s) {
      short8 af[4], bfr[4];
#pragma unroll
      for (int i = 0; i < 4; ++i)
        af[i] = *(const short8*)&As[wm + i * 16 + col][((s * 4 + quad) ^ sw) * 8];
#pragma unroll
      for (int j = 0; j < 4; ++j)
        bfr[j] = *(const short8*)&Bs[wn + j * 16 + col][((s * 4 + quad) ^ sw) * 8];
#pragma unroll
      for (int i = 0; i < 4; ++i)
#pragma unroll
        for (int j = 0; j < 4; ++j)
          acc[i][j] = __builtin_amdgcn_mfma_f32_16x16x32_bf16(af[i], bfr[j], acc[i][j], 0, 0, 0);
    }
    __syncthreads();
  }

  // EPI 2: combine the 32 rowsum partials once per block (Bs is free now).
  float* invb = (float*)Bs;
  if (EPI == 2) {
    if (t < 128) {
      float s = 0.f;
#pragma unroll
      for (int p = 0; p < 32; ++p) s += aux[p * 8192 + m0 + t];
      invb[t] = __builtin_amdgcn_rcpf(s);
    }
    __syncthreads();
  }

  // C/D layout: col = lane&15, row = quad*4 + reg  (m89-verified)
  const float LOG2E = 1.44269504f;
  const float c1 = scale * LOG2E;
#pragma unroll
  for (int i = 0; i < 4; ++i) {
    float invv[4], addm[4], rsum4[4] = {0.f, 0.f, 0.f, 0.f};
    if (EPI == 2) {
#pragma unroll
      for (int r = 0; r < 4; ++r) invv[r] = invb[wm + i * 16 + quad * 4 + r];
    }
    if (EPI == 3) {
#pragma unroll
      for (int r = 0; r < 4; ++r) addm[r] = aux[m0 + wm + i * 16 + quad * 4 + r];
    }
#pragma unroll
    for (int j = 0; j < 4; ++j) {
      const int n = n0 + wn + j * 16 + col;
      float addn = 0.f;
      if (EPI == 0) addn = aux[n];
#pragma unroll
      for (int r = 0; r < 4; ++r) {
        const int m = m0 + wm + i * 16 + quad * 4 + r;
        float v = acc[i][j][r];
        if (EPI == 0) {
          ((short*)C)[(long)m * N + n] = f2bf(v + addn);
        } else if (EPI == 1) {
          float mv = aux[(long)m * N + n];
          float e = exp2f(fmaf(v, c1, mv * LOG2E));  // exp(v*scale+mask); |s|~3, safe
          short q = f2bf(e);
          ((short*)C)[(long)m * N + n] = q;
          rsum4[r] += bf2f(q);  // sum exactly what PV will read
        } else if (EPI == 2) {
          ((float*)C)[(long)m * N + n] = v * invv[r];
        } else {
          ((short*)C)[(long)m * N + n] = f2bf(v + addm[r]);
        }
      }
    }
    if (EPI == 1) {
      // reduce across the 16 lanes of this quad-group; one slot per wave-n-half
#pragma unroll
      for (int r = 0; r < 4; ++r) {
        float s = rsum4[r];
        s += __shfl_xor(s, 1);
        s += __shfl_xor(s, 2);
        s += __shfl_xor(s, 4);
        s += __shfl_xor(s, 8);
        if (col == 0)
          rsum[(wn >> 6) * 8192 + m0 + wm + i * 16 + quad * 4 + r] = s;
      }
    }
  }
}

// ---------- QK (blocks 0..1023) + Vt (1024..1535), XCD-swizzled ----------
__global__ __launch_bounds__(256) void qkv_kernel(const short* __restrict__ x_bf,
                                                  const short* __restrict__ w_bf,
                                                  short* __restrict__ QK,
                                                  short* __restrict__ Vt,
                                                  const float* __restrict__ bcat,
                                                  const float* __restrict__ bv) {
  __shared__ alignas(16) short As[128][64];
  __shared__ alignas(16) short Bs[128][64];
  const int b = blockIdx.x;
  if (b < 1024) {
    // xcd slab of 128 tiles, n-fast: consecutive same-XCD blocks share A panel
    const int g = (b & 7) * 128 + (b >> 3);
    const int bz = g >> 9, rr = g & 511;
    const int m0 = (rr >> 3) * 128, n0 = (rr & 7) * 128;
    gemm_body<0>(x_bf, w_bf + (long)bz * 1048576, QK + (long)bz * 8388608,
                 bcat + bz * 1024, nullptr, 1.f, 1024, 1024, 1024, m0, n0, As, Bs);
  } else {
    const int v = b - 1024;
    const int g = (v & 7) * 64 + (v >> 3);   // each XCD: one w_v m-tile, all n
    const int m0 = (g >> 6) * 128, n0 = (g & 63) * 128;
    gemm_body<3>(w_bf + 2097152, x_bf, Vt, bv, nullptr, 1.f,
                 8192, 1024, 1024, m0, n0, As, Bs);
  }
}

// ---------- P = exp(Q K^T /32 + mask), partial rowsums -> rspart ----------
__global__ __launch_bounds__(256) void scores_kernel(const short* __restrict__ Q,
                                                     const short* __restrict__ Kb,
                                                     short* __restrict__ P,
                                                     const float* __restrict__ mask,
                                                     float* __restrict__ rspart) {
  __shared__ alignas(16) short As[128][64];
  __shared__ alignas(16) short Bs[128][64];
  const int id = blockIdx.x;                 // 1024
  const int g = (id & 7) * 128 + (id >> 3);  // per-XCD slab, n-fast
  const int bz = g >> 8, t2 = g & 255;
  const int m0 = (t2 >> 4) * 128, n0 = (t2 & 15) * 128;
  // slot base: 2 slots per n-tile (one per wave-n-half), [32][4][2048] layout
  gemm_body<1>(Q + (long)bz * 2097152, Kb + (long)bz * 2097152,
               P + (long)bz * 4194304, mask,
               rspart + (n0 >> 7) * 2 * 8192 + bz * 2048, 0.03125f,
               2048, 1024, 1024, m0, n0, As, Bs);
}

// ---------- out = (P V) / rowsum, 128x128 ----------
__global__ __launch_bounds__(256) void pv_kernel(const short* __restrict__ P,
                                                 const short* __restrict__ Vt,
                                                 float* __restrict__ out,
                                                 const float* __restrict__ rspart) {
  __shared__ alignas(16) short As[128][64];
  __shared__ alignas(16) short Bs[128][64];
  const int id = blockIdx.x;                // 512
  const int g = (id & 7) * 64 + (id >> 3);  // per-XCD slab, n-fast
  const int bz = g >> 7, t2 = g & 127;
  const int m0 = (t2 >> 3) * 128, n0 = (t2 & 7) * 128;
  gemm_body<2>(P + (long)bz * 4194304, Vt + (long)bz * 2048,
               out + (long)bz * 2097152, rspart + bz * 2048, nullptr, 1.f,
               1024, 2048, 8192, m0, n0, As, Bs);
}

extern "C" void kernel_launch(void* const* d_in, const int* in_sizes, int n_in,
                              void* d_out, int out_size, void* d_ws, size_t ws_size,
                              hipStream_t stream) {
  const float* x    = (const float*)d_in[0];
  const float* mask = (const float*)d_in[1];
  const float* wq   = (const float*)d_in[2];
  const float* bq   = (const float*)d_in[3];
  const float* wk   = (const float*)d_in[4];
  const float* bk   = (const float*)d_in[5];
  const float* wv   = (const float*)d_in[6];
  const float* bv   = (const float*)d_in[7];
  float* out = (float*)d_out;

  char* ws = (char*)d_ws;
  const size_t MB = 1024 * 1024;
  short* x_bf   = (short*)(ws);             // 16 MB [8192,1024]; dead after qkv
  float* rspart = (float*)(ws);             // 1 MB [32][4][2048], aliases x_bf
  short* w_bf   = (short*)(ws + 16 * MB);   // 6 MB [3][1024,1024]
  short* QK     = (short*)(ws + 22 * MB);   // 32 MB [2][8192,1024]
  short* Vt     = (short*)(ws + 54 * MB);   // 16 MB [1024][8192] = [d][b*2048+s]
  short* P      = (short*)(ws + 70 * MB);   // 32 MB [4][2048][2048] (unnormalized exp)
  float* bcat   = (float*)(ws + 70 * MB);   // 8 KB, aliases head of P (dead before P)

  prep_kernel<<<11272, 256, 0, stream>>>(x, wq, wk, wv, bq, bk, x_bf, w_bf, bcat);

  // QK projections (z=2) + Vt GEMM, one launch, XCD-swizzled
  qkv_kernel<<<1536, 256, 0, stream>>>(x_bf, w_bf, QK, Vt, bcat, bv);

  short* Q  = QK;
  short* Kb = QK + 8388608;

  // P = exp(Q K^T / 32 + mask) -> bf16 unnormalized; rspart gets partial sums
  scores_kernel<<<1024, 256, 0, stream>>>(Q, Kb, P, mask, rspart);

  // out = (P V) / rowsum
  pv_kernel<<<512, 256, 0, stream>>>(P, Vt, out, rspart);
}